// Round 1
// baseline (1286.965 us; speedup 1.0000x reference)
//
#include <hip/hip_runtime.h>
#include <float.h>

#define HIDDEN 128
#define OUTW (3 * HIDDEN)

// One block per segment. batch is sorted, so segment b occupies rows
// [lower_bound(b), lower_bound(b+1)). 256 threads = 4 waves; each wave64
// covers 2 adjacent rows (32 lanes x float4 = 512B/row), so the wave reads
// 1KB contiguous per iteration and the block strides 8 rows.
__global__ __launch_bounds__(256) void deepsets_pool_kernel(
    const float* __restrict__ x,
    const int* __restrict__ batch,
    float* __restrict__ out,
    int N)
{
    const int b = blockIdx.x;

    // lower_bound(b): first i with batch[i] >= b   (wave-uniform, broadcast loads)
    int lo = 0, hi = N;
    while (lo < hi) {
        int mid = (lo + hi) >> 1;
        if (batch[mid] < b) lo = mid + 1; else hi = mid;
    }
    const int start = lo;
    // lower_bound(b+1)
    hi = N;
    while (lo < hi) {
        int mid = (lo + hi) >> 1;
        if (batch[mid] < b + 1) lo = mid + 1; else hi = mid;
    }
    const int end = lo;
    const int count = end - start;

    const int tid  = threadIdx.x;
    const int wave = tid >> 6;       // 0..3
    const int lane = tid & 63;
    const int sub  = lane >> 5;      // which row of the wave's pair: 0/1
    const int fl   = lane & 31;      // feature lane: handles floats 4*fl..4*fl+3

    float4 s  = make_float4(0.f, 0.f, 0.f, 0.f);
    float4 mx = make_float4(-FLT_MAX, -FLT_MAX, -FLT_MAX, -FLT_MAX);

    for (int r = start + wave * 2 + sub; r < end; r += 8) {
        const float4 v = *reinterpret_cast<const float4*>(
            x + (size_t)r * HIDDEN + (size_t)fl * 4);
        s.x += v.x; s.y += v.y; s.z += v.z; s.w += v.w;
        mx.x = fmaxf(mx.x, v.x); mx.y = fmaxf(mx.y, v.y);
        mx.z = fmaxf(mx.z, v.z); mx.w = fmaxf(mx.w, v.w);
    }

    // Fold row pair: lane i <- lane i+32 (wave64 shuffle)
    s.x += __shfl_down(s.x, 32); s.y += __shfl_down(s.y, 32);
    s.z += __shfl_down(s.z, 32); s.w += __shfl_down(s.w, 32);
    mx.x = fmaxf(mx.x, __shfl_down(mx.x, 32));
    mx.y = fmaxf(mx.y, __shfl_down(mx.y, 32));
    mx.z = fmaxf(mx.z, __shfl_down(mx.z, 32));
    mx.w = fmaxf(mx.w, __shfl_down(mx.w, 32));

    __shared__ float4 lds_s[4][32];
    __shared__ float4 lds_m[4][32];
    if (sub == 0) {
        lds_s[wave][fl] = s;
        lds_m[wave][fl] = mx;
    }
    __syncthreads();

    if (tid < 32) {
        float4 ts = lds_s[0][tid];
        float4 tm = lds_m[0][tid];
        #pragma unroll
        for (int w = 1; w < 4; ++w) {
            float4 os = lds_s[w][tid];
            ts.x += os.x; ts.y += os.y; ts.z += os.z; ts.w += os.w;
            float4 om = lds_m[w][tid];
            tm.x = fmaxf(tm.x, om.x); tm.y = fmaxf(tm.y, om.y);
            tm.z = fmaxf(tm.z, om.z); tm.w = fmaxf(tm.w, om.w);
        }
        const float inv = 1.0f / fmaxf((float)count, 1.0f);
        float4 mean = make_float4(ts.x * inv, ts.y * inv, ts.z * inv, ts.w * inv);
        if (count == 0) tm = make_float4(0.f, 0.f, 0.f, 0.f);

        float* ob = out + (size_t)b * OUTW;
        *reinterpret_cast<float4*>(ob + tid * 4)              = ts;   // sum
        *reinterpret_cast<float4*>(ob + HIDDEN + tid * 4)     = mean; // mean
        *reinterpret_cast<float4*>(ob + 2 * HIDDEN + tid * 4) = tm;   // max
    }
}

extern "C" void kernel_launch(void* const* d_in, const int* in_sizes, int n_in,
                              void* d_out, int out_size, void* d_ws, size_t ws_size,
                              hipStream_t stream) {
    const float* x     = (const float*)d_in[0];
    const int*   batch = (const int*)d_in[1];
    float*       out   = (float*)d_out;

    const int N = in_sizes[1];            // 2,000,000 rows
    const int B = out_size / OUTW;        // 4096 segments

    deepsets_pool_kernel<<<B, 256, 0, stream>>>(x, batch, out, N);
}